// Round 1
// baseline (23.516 us; speedup 1.0000x reference)
//
#include <hip/hip_runtime.h>

#define NQ 4
#define DIMQ 16
#define NLAY 8
#define NOUT 4

// ---------------------------------------------------------------------------
// Setup kernel (1 block, 256 threads): builds the three folded 16x16 matrices
//   A_m = 0.5 * ( sum_{k<4} ent0[k]^2 * U_k^T D_m U_k  +  (sum_{k>=4} ent0[k]^2) * D_m )
// where D_m = diag(sign of bit (3-m)), U_k the k-th QNN unitary.
// Then out[b][m] = 0.5 + enc^T A_m enc.
// ---------------------------------------------------------------------------
__global__ __launch_bounds__(256) void qnn_setup(const float* __restrict__ alpha,
                                                 const float* __restrict__ thetas,
                                                 float* __restrict__ A_out) {
    __shared__ float U[NOUT][DIMQ][DIMQ];  // U[k][row][col]
    __shared__ float w[5];                 // w[0..3] = ent0[k]^2, w[4] = sum_{k>=4}
    const int tid = threadIdx.x;

    // Threads 0..63: simulate column `col` of unitary `k` (state-vector, 16 amps)
    if (tid < 64) {
        const int k = tid >> 4, col = tid & 15;
        float st[16];
        #pragma unroll
        for (int i = 0; i < 16; ++i) st[i] = (i == col) ? 1.0f : 0.0f;
        const float* th = thetas + k * (NLAY * NQ);
        for (int l = 0; l < NLAY; ++l) {
            // RY on each qubit q (qubit 0 = MSB -> bit position 3-q)
            for (int q = 0; q < NQ; ++q) {
                const float t = th[l * NQ + q] * 0.5f;
                const float c = cosf(t), s = sinf(t);
                const int pb = 1 << (3 - q);
                #pragma unroll
                for (int i0 = 0; i0 < 16; ++i0) {
                    if (i0 & pb) continue;
                    const int i1 = i0 | pb;
                    const float a0 = st[i0], a1 = st[i1];
                    st[i0] = c * a0 - s * a1;   // RY = [[c,-s],[s,c]]
                    st[i1] = s * a0 + c * a1;
                }
            }
            // Entangler: CNOT(0,1), CNOT(1,2), CNOT(2,3) in that order.
            // CNOT(q,q+1): control bit (3-q), target bit (2-q). As a permutation
            // on amplitudes: swap amp[i] <-> amp[i|tb] for i with cb set, tb clear.
            for (int q = 0; q < NQ - 1; ++q) {
                const int cb = 1 << (3 - q), tb = 1 << (2 - q);
                #pragma unroll
                for (int i = 0; i < 16; ++i) {
                    if ((i & cb) && !(i & tb)) {
                        const int j = i | tb;
                        const float tmp = st[i]; st[i] = st[j]; st[j] = tmp;
                    }
                }
            }
        }
        #pragma unroll
        for (int r = 0; r < 16; ++r) U[k][r][col] = st[r];
    }

    // Thread 64: ancilla tree state ent0 = (L2 @ L1 @ L0)|0> and the weights.
    if (tid == 64) {
        float e[8];
        #pragma unroll
        for (int i = 0; i < 8; ++i) e[i] = (i == 0) ? 1.0f : 0.0f;
        int idx = 0;
        for (int l = 0; l < 3; ++l) {
            const int p = 2 - l, pb = 1 << p;
            #pragma unroll
            for (int i0 = 0; i0 < 8; ++i0) {
                if (i0 & pb) continue;
                const int i1 = i0 | pb;
                const int blk = i0 >> (p + 1);          // which RY block in this layer
                const float t = alpha[idx + blk] * 0.5f;
                const float c = cosf(t), s = sinf(t);
                const float a0 = e[i0], a1 = e[i1];
                e[i0] = c * a0 - s * a1;
                e[i1] = s * a0 + c * a1;
            }
            idx += (1 << l);
        }
        for (int k = 0; k < 4; ++k) w[k] = e[k] * e[k];
        w[4] = e[4]*e[4] + e[5]*e[5] + e[6]*e[6] + e[7]*e[7];
    }

    __syncthreads();

    // 256 threads: entry (t,u) of all three A matrices.
    const int t = tid >> 4, u = tid & 15;
    for (int m = 0; m < 3; ++m) {
        const int bit = 3 - m;  // e3 -> bit3, e4 -> bit2, e5 -> bit1
        float acc = (t == u) ? (((t >> bit) & 1) ? -w[4] : w[4]) : 0.0f;
        for (int k = 0; k < NOUT; ++k) {
            float sk = 0.0f;
            #pragma unroll
            for (int r = 0; r < 16; ++r) {
                const float sg = ((r >> bit) & 1) ? -1.0f : 1.0f;
                sk = fmaf(U[k][r][t] * sg, U[k][r][u], sk);
            }
            acc = fmaf(w[k], sk, acc);
        }
        A_out[(m * 16 + t) * 16 + u] = 0.5f * acc;  // fold (e+1)*0.5
    }
}

// ---------------------------------------------------------------------------
// Main kernel: one thread per sample.
// ---------------------------------------------------------------------------
__global__ __launch_bounds__(256) void qnn_main(const float4* __restrict__ x,
                                                const float* __restrict__ A,
                                                float* __restrict__ out,
                                                int batch) {
    __shared__ float sA[3][16][16];
    const int tid = threadIdx.x;
    #pragma unroll
    for (int i = tid; i < 768; i += 256) ((float*)sA)[i] = A[i];
    __syncthreads();

    const int b = blockIdx.x * 256 + tid;
    if (b >= batch) return;

    const float4 xv = x[b];
    float c[4], s[4];
    sincospif(xv.x, &s[0], &c[0]);  // cos(pi*x), sin(pi*x)
    sincospif(xv.y, &s[1], &c[1]);
    sincospif(xv.z, &s[2], &c[2]);
    sincospif(xv.w, &s[3], &c[3]);

    float enc[16];
    #pragma unroll
    for (int t = 0; t < 16; ++t) {
        float v = ((t & 8) ? s[0] : c[0]);
        v *= ((t & 4) ? s[1] : c[1]);
        v *= ((t & 2) ? s[2] : c[2]);
        v *= ((t & 1) ? s[3] : c[3]);
        enc[t] = v;
    }

    float e0 = 0.5f, e1 = 0.5f, e2 = 0.5f;
    #pragma unroll
    for (int t = 0; t < 16; ++t) {
        float ay0 = 0.0f, ay1 = 0.0f, ay2 = 0.0f;
        #pragma unroll
        for (int u = 0; u < 16; ++u) {
            const float ev = enc[u];   // sA reads are lane-uniform -> LDS broadcast
            ay0 = fmaf(sA[0][t][u], ev, ay0);
            ay1 = fmaf(sA[1][t][u], ev, ay1);
            ay2 = fmaf(sA[2][t][u], ev, ay2);
        }
        e0 = fmaf(enc[t], ay0, e0);
        e1 = fmaf(enc[t], ay1, e1);
        e2 = fmaf(enc[t], ay2, e2);
    }

    out[b * 3 + 0] = e0;
    out[b * 3 + 1] = e1;
    out[b * 3 + 2] = e2;
}

extern "C" void kernel_launch(void* const* d_in, const int* in_sizes, int n_in,
                              void* d_out, int out_size, void* d_ws, size_t ws_size,
                              hipStream_t stream) {
    const float* x      = (const float*)d_in[0];   // (131072, 4) f32
    const float* alpha  = (const float*)d_in[1];   // (7,) f32
    const float* thetas = (const float*)d_in[2];   // (4, 32) f32
    float* A = (float*)d_ws;                       // 3*16*16 floats scratch

    qnn_setup<<<1, 256, 0, stream>>>(alpha, thetas, A);

    const int batch = in_sizes[0] / 4;
    const int blocks = (batch + 255) / 256;
    qnn_main<<<blocks, 256, 0, stream>>>((const float4*)x, A, (float*)d_out, batch);
}